// Round 13
// baseline (827.040 us; speedup 1.0000x reference)
//
#include <hip/hip_runtime.h>
#include <hip/hip_bf16.h>

typedef __hip_bfloat16 bf16;
typedef __bf16 bf16x8 __attribute__((ext_vector_type(8)));
typedef float f32x4 __attribute__((ext_vector_type(4)));

#define MEAN0 0.4488f
#define MEAN1 0.4371f
#define MEAN2 0.4040f

// ---------------- IICM: 3->12 conv3x3 per 32x32 patch, relu -> NHWC-16 bf16 + partials (|f|, v, v^2) ----------------
__global__ void k_iicm(const float* __restrict__ x, const float* __restrict__ w,
                       const float* __restrict__ bias, bf16* __restrict__ outN16,
                       float* __restrict__ partial){
  __shared__ __align__(16) float ws_[324];   // [tap27][oc12]
  __shared__ float bs[12];
  __shared__ float sh[256];
  for(int k=threadIdx.x;k<324;k+=256){ int t0=k/12, kk=k%12; ws_[k]=w[kk*27+t0]; }
  if(threadIdx.x<12) bs[threadIdx.x]=bias[threadIdx.x];
  __syncthreads();
  int idx = blockIdx.x*256+threadIdx.x;
  int pix = idx & 1023, n = idx >> 10;
  int i = pix>>5, j = pix&31;
  int pw = n%5, ph=(n/5)%5, bb=n/25;
  float acc[12];
  #pragma unroll
  for(int k=0;k<12;k++) acc[k]=bs[k];
  #pragma unroll
  for(int c=0;c<3;c++){
    const float* xb = x + ((bb*3+c)*160 + ph*32)*160 + pw*32;
    float mc = (c==0)?MEAN0:((c==1)?MEAN1:MEAN2);
    #pragma unroll
    for(int dy=-1;dy<=1;dy++){
      int ii=i+dy; if((unsigned)ii>=32u) continue;
      #pragma unroll
      for(int dx=-1;dx<=1;dx++){
        int jj=j+dx; if((unsigned)jj>=32u) continue;
        float v = xb[ii*160+jj]-mc;
        int t0 = c*9+(dy+1)*3+(dx+1);
        const float4* wv = (const float4*)&ws_[t0*12];
        float4 w0=wv[0], w1=wv[1], w2=wv[2];
        acc[0]+=v*w0.x; acc[1]+=v*w0.y; acc[2]+=v*w0.z; acc[3]+=v*w0.w;
        acc[4]+=v*w1.x; acc[5]+=v*w1.y; acc[6]+=v*w1.z; acc[7]+=v*w1.w;
        acc[8]+=v*w2.x; acc[9]+=v*w2.y; acc[10]+=v*w2.z; acc[11]+=v*w2.w;
      }
    }
  }
  float s=0.f;
  #pragma unroll
  for(int k=0;k<12;k++){ acc[k]=fmaxf(acc[k],0.f); s+=acc[k]; }
  union{ float4 v; bf16 h[8]; } p0, p1;
  #pragma unroll
  for(int k=0;k<8;k++) p0.h[k]=__float2bfloat16(acc[k]);
  #pragma unroll
  for(int k=0;k<4;k++) p1.h[k]=__float2bfloat16(acc[8+k]);
  #pragma unroll
  for(int k=4;k<8;k++) p1.h[k]=__float2bfloat16(0.f);
  bf16* o16 = outN16 + (size_t)(n*1024+pix)*16;
  *(float4*)o16 = p0.v;
  *(float4*)(o16+8) = p1.v;
  const float* xb0 = x + ((bb*3)*160 + ph*32)*160 + pw*32;
  float v0 = xb0[i*160+j]-MEAN0;
  sh[threadIdx.x]=s; __syncthreads();
  for(int o=128;o>0;o>>=1){ if(threadIdx.x<o) sh[threadIdx.x]+=sh[threadIdx.x+o]; __syncthreads(); }
  if(threadIdx.x==0) partial[blockIdx.x*4+0]=sh[0];
  __syncthreads();
  sh[threadIdx.x]=v0; __syncthreads();
  for(int o=128;o>0;o>>=1){ if(threadIdx.x<o) sh[threadIdx.x]+=sh[threadIdx.x+o]; __syncthreads(); }
  if(threadIdx.x==0) partial[blockIdx.x*4+1]=sh[0];
  __syncthreads();
  sh[threadIdx.x]=v0*v0; __syncthreads();
  for(int o=128;o>0;o>>=1){ if(threadIdx.x<o) sh[threadIdx.x]+=sh[threadIdx.x+o]; __syncthreads(); }
  if(threadIdx.x==0) partial[blockIdx.x*4+2]=sh[0];
}

// ---------------- unified weight pack (all convs) ----------------
__global__ void k_wpack(const float* __restrict__ c1_w, const float* __restrict__ c2_w,
                        const float* __restrict__ c3_w, const float* __restrict__ up1_w,
                        const float* __restrict__ up2_w, const float* __restrict__ marm_w,
                        const float* __restrict__ upc_w, const float* __restrict__ b1_w1,
                        const float* __restrict__ b1_w2, const float* __restrict__ b2_w1,
                        const float* __restrict__ b2_w2, const float* __restrict__ b3_w1,
                        const float* __restrict__ b3_w2, const float* __restrict__ conv4_w,
                        bf16* __restrict__ packs){
  int idx = blockIdx.x*256+threadIdx.x;
  if(idx>=467968) return;
  float v;
  if(idx<36864){
    const float* w; int Cin, base;
    if(idx<8192){ w=c1_w; Cin=128; base=0; }
    else if(idx<20480){ w=c2_w; Cin=192; base=8192; }
    else { w=c3_w; Cin=256; base=20480; }
    int r=idx-base; int g=r>>9, oc=(r>>3)&63, j=r&7;
    v = w[oc*Cin + g*8 + j];
  } else if(idx<331776){
    int r0=idx-36864;
    int conv=r0/147456; int r=r0-conv*147456;
    int tap=r>>14; int r2=r&16383;
    int s=(r2>>11)&7, oc=(r2>>3)&255, j=r2&7;
    int ic=s*8+j;
    const float* w = conv? up2_w : up1_w;
    v = w[oc*576 + ic*9 + tap];
  } else if(idx<387072){
    int r=idx-331776;
    int tap=r/6144; int rr=r-tap*6144;
    int icg=rr>>9, oc=(rr>>3)&63, j=rr&7;
    int ic=icg*8+j;
    v = 0.f;
    if(ic<64)      v = marm_w[oc*603 + (3+ic)*9 + tap];
    else if(ic<67) v = marm_w[oc*603 + (ic-64)*9 + tap];
  } else if(idx<396288){
    int r=idx-387072;
    int tap=r>>10; int rr=r&1023;
    int tc=rr>>7, oc=(rr>>3)&15, j=rr&7;
    int ic=tc*8+j;
    v = (oc<3) ? upc_w[oc*576 + ic*9 + tap] : 0.f;
  } else if(idx<457728){
    int r=idx-396288;
    int conv=r/10240; int rr=r-conv*10240;
    int tp=rr/2048; int r2=rr&2047;
    int oc=r2>>5; int k=r2&31;
    int ks=k>>3, e=k&7;
    int tap=2*tp+(ks>>1);
    int il=(ks&1)*8+e;
    const float* w = (conv==0)?b1_w1:(conv==1)?b1_w2:(conv==2)?b2_w1:(conv==3)?b2_w2:(conv==4)?b3_w1:b3_w2;
    v = (tap<9) ? w[oc*144 + il*9 + tap] : 0.f;
  } else {
    int r=idx-457728;
    int tp=r/2048; int r2=r&2047;
    int oc=r2>>5; int k=r2&31;
    int ks=k>>3, e=k&7;
    int tap=2*tp+(ks>>1);
    int ic=(ks&1)*8+e;
    v = (tap<9 && ic<12) ? conv4_w[oc*108 + ic*9 + tap] : 0.f;
  }
  packs[idx]=__float2bfloat16(v);
}

// ---------------- conv4 MFMA (tap-packed) + scal-finish tail blocks ----------------
__global__ __launch_bounds__(128,3) void k_conv4M(const bf16* __restrict__ in,
                        const bf16* __restrict__ wp4, const float* __restrict__ bias,
                        bf16* __restrict__ outN, const float* __restrict__ partial,
                        float* __restrict__ scalp, int nconv){
  int tid=threadIdx.x, bid=blockIdx.x;
  if(bid >= nconv){
    if(tid==0){
      int n = bid - nconv;
      float s=0.f, sm=0.f, sq=0.f;
      #pragma unroll
      for(int q=0;q<4;q++){
        s  += partial[(n*4+q)*4+0];
        sm += partial[(n*4+q)*4+1];
        sq += partial[(n*4+q)*4+2];
      }
      scalp[n] = s*(1.f/12288.f);
      float smean = sm*(1.f/1024.f);
      float var = sq*(1.f/1024.f) - smean*smean;
      scalp[128+n] = sqrtf(fmaxf(var,0.f));
    }
    return;
  }
  __shared__ __align__(16) __bf16 sB[204*2*8];   // 6528 B
  int n=bid>>3, tile=bid&7, y0=tile*4;
  const bf16* ib = in + (size_t)n*16384;
  for(int cid=tid; cid<408; cid+=128){
    int p=cid>>1, c=cid&1;
    int r=p/34, cc=p-r*34;
    int gy=y0-1+r, gx=cc-1;
    float4 v={0.f,0.f,0.f,0.f};
    if((unsigned)gy<32u && (unsigned)gx<32u)
      v = *(const float4*)(ib + (size_t)((gy<<5)+gx)*16 + c*8);
    *(float4*)(&sB[(size_t)(p*2 + (c^(p&1)))*8]) = v;
  }
  __syncthreads();
  int w_=tid>>6, l=tid&63;
  int ks=l>>4, l15=l&15;
  int h=ks>>1, cb=ks&1;
  f32x4 acc[4][4];
  #pragma unroll
  for(int i=0;i<4;i++)
    #pragma unroll
    for(int j=0;j<4;j++) acc[i][j]=(f32x4){0.f,0.f,0.f,0.f};
  int pr[4], pc[4];
  #pragma unroll
  for(int fn=0;fn<4;fn++){ int npx=w_*64+fn*16+l15; pr[fn]=npx>>5; pc[fn]=npx&31; }
  #pragma unroll
  for(int tp=0;tp<5;tp++){
    bf16x8 afr[4];
    #pragma unroll
    for(int fm=0;fm<4;fm++)
      afr[fm] = *(const bf16x8*)(wp4 + (((size_t)(tp*64 + fm*16 + l15))*4 + ks)*8);
    #pragma unroll
    for(int fm=0;fm<4;fm++) asm volatile("" : "+v"(afr[fm]));
    const int t0=2*tp, t1=(2*tp+1>8)?8:(2*tp+1);
    int ty = h ? (t1/3) : (t0/3);
    int tx = h ? (t1%3) : (t0%3);
    #pragma unroll
    for(int fn=0;fn<4;fn++){
      int p = (pr[fn]+ty)*34 + pc[fn]+tx;
      bf16x8 b = *(const bf16x8*)(&sB[(size_t)(p*2 + (cb^(p&1)))*8]);
      #pragma unroll
      for(int fm=0;fm<4;fm++)
        acc[fm][fn] = __builtin_amdgcn_mfma_f32_16x16x32_bf16(afr[fm], b, acc[fm][fn], 0,0,0);
    }
  }
  bf16* ob = outN + (size_t)n*65536;
  #pragma unroll
  for(int fm=0;fm<4;fm++){
    int oc0 = fm*16 + ks*4;
    #pragma unroll
    for(int fn=0;fn<4;fn++){
      int pxl = (y0+pr[fn])*32 + pc[fn];
      union{ uint2 u; bf16 hh[4]; } pk;
      #pragma unroll
      for(int j=0;j<4;j++) pk.hh[j]=__float2bfloat16(acc[fm][fn][j]+bias[oc0+j]);
      *(uint2*)(ob + (size_t)pxl*64 + oc0) = pk.u;
    }
  }
}

// ---------------- grouped MFMA conv (tap-packed, proper groups): 64->64 conv3x3 per patch ----------------
__global__ __launch_bounds__(128,3) void k_gconvM(const bf16* __restrict__ in,
                        const bf16* __restrict__ wg, const float* __restrict__ bias,
                        const bf16* __restrict__ resid, bf16* __restrict__ out, int do_relu){
  __shared__ __align__(16) __bf16 sB[204*8*8];   // 26112 B
  int tid = threadIdx.x;
  int bid = blockIdx.x;
  int n = bid>>3, tile = bid&7;
  int y0 = tile*4;
  const bf16* ib = in + (size_t)n*65536;
  for(int cid=tid; cid<1632; cid+=128){
    int p = cid>>3, s = cid&7;
    int r = p/34, c = p - r*34;
    int gy = y0-1+r, gx = c-1;
    float4 v = {0.f,0.f,0.f,0.f};
    if((unsigned)gy<32u && (unsigned)gx<32u)
      v = *(const float4*)(ib + (size_t)((gy<<5)+gx)*64 + s*8);
    *(float4*)(&sB[(size_t)(p*8 + (s^(p&7)))*8]) = v;
  }
  __syncthreads();
  int w_ = tid>>6, l = tid&63;
  int ks = l>>4, l15 = l&15;
  int h = ks>>1, cb = ks&1;
  f32x4 acc[4][4];
  #pragma unroll
  for(int i=0;i<4;i++)
    #pragma unroll
    for(int j=0;j<4;j++) acc[i][j]=(f32x4){0.f,0.f,0.f,0.f};
  int pr[4], pc[4];
  #pragma unroll
  for(int fn=0;fn<4;fn++){ int npx = w_*64+fn*16+l15; pr[fn]=npx>>5; pc[fn]=npx&31; }
  #pragma unroll
  for(int tp=0;tp<5;tp++){
    bf16x8 afr[4];
    #pragma unroll
    for(int fm=0;fm<4;fm++)
      afr[fm] = *(const bf16x8*)(wg + (((size_t)(tp*64 + fm*16 + l15))*4 + ks)*8);
    #pragma unroll
    for(int fm=0;fm<4;fm++) asm volatile("" : "+v"(afr[fm]));
    const int t0=2*tp, t1=(2*tp+1>8)?8:(2*tp+1);
    int ty = h ? (t1/3) : (t0/3);
    int tx = h ? (t1%3) : (t0%3);
    #pragma unroll
    for(int fn=0;fn<4;fn++){
      int p = (pr[fn]+ty)*34 + pc[fn]+tx;
      int pb = p*8;
      #pragma unroll
      for(int fm=0;fm<4;fm++){
        int c = fm*2 + cb;
        bf16x8 b = *(const bf16x8*)(&sB[(size_t)(pb + (c^(p&7)))*8]);
        acc[fm][fn] = __builtin_amdgcn_mfma_f32_16x16x32_bf16(afr[fm], b, acc[fm][fn], 0,0,0);
      }
    }
  }
  bf16* ob = out + (size_t)n*65536;
  const bf16* rb = resid ? resid + (size_t)n*65536 : (const bf16*)0;
  #pragma unroll
  for(int fm=0;fm<4;fm++){
    int oc0 = fm*16 + ks*4;
    #pragma unroll
    for(int fn=0;fn<4;fn++){
      int pxl = (y0+pr[fn])*32 + pc[fn];
      float v[4];
      #pragma unroll
      for(int j=0;j<4;j++){
        float t = acc[fm][fn][j] + bias[oc0+j];
        if(do_relu) t = fmaxf(t,0.f);
        v[j]=t;
      }
      if(rb){
        union{ uint2 u; bf16 h[4]; } ru;
        ru.u = *(const uint2*)(rb + (size_t)pxl*64 + oc0);
        #pragma unroll
        for(int j=0;j<4;j++) v[j] += __bfloat162float(ru.h[j]);
      }
      union{ uint2 u; bf16 h[4]; } pk;
      #pragma unroll
      for(int j=0;j<4;j++) pk.h[j]=__float2bfloat16(v[j]);
      *(uint2*)(ob + (size_t)pxl*64 + oc0) = pk.u;
    }
  }
}

// ---------------- MFMA 1x1 conv (pure GEMM): A from L2, B staged; relu ----------------
__global__ __launch_bounds__(256,4) void k_1x1M(const bf16* __restrict__ s0,
                        const bf16* __restrict__ s1, const bf16* __restrict__ s2,
                        const bf16* __restrict__ s3, int ns,
                        const bf16* __restrict__ wpk, const float* __restrict__ bias,
                        bf16* __restrict__ outN){
  __shared__ __align__(16) __bf16 sB[8*256*8];   // 32768 B
  int tid = threadIdx.x;
  int px0 = blockIdx.x*256;
  int w_ = tid>>6, l = tid&63;
  int ks = l>>4, l15 = l&15;
  f32x4 acc[4][4];
  #pragma unroll
  for(int i=0;i<4;i++)
    #pragma unroll
    for(int j=0;j<4;j++) acc[i][j]=(f32x4){0.f,0.f,0.f,0.f};
  const bf16* srcs[4]={s0,s1,s2,s3};
  for(int s=0;s<ns;s++){
    __syncthreads();
    const bf16* sp = srcs[s];
    #pragma unroll
    for(int it=0;it<8;it++){
      *(float4*)(&sB[(size_t)(it*256+tid)*8]) = *(const float4*)(sp + (size_t)(px0+tid)*64 + it*8);
    }
    __syncthreads();
    #pragma unroll
    for(int kk=0;kk<2;kk++){
      int tc = kk*4+ks;
      bf16x8 a[4], b[4];
      #pragma unroll
      for(int fm=0;fm<4;fm++)
        a[fm] = *(const bf16x8*)(wpk + ((size_t)((s*8+tc)*64 + fm*16+l15))*8);
      #pragma unroll
      for(int fm=0;fm<4;fm++) asm volatile("" : "+v"(a[fm]));
      #pragma unroll
      for(int fn=0;fn<4;fn++) b[fn] = *(const bf16x8*)(&sB[(size_t)(tc*256 + w_*64+fn*16+l15)*8]);
      #pragma unroll
      for(int fm=0;fm<4;fm++)
        #pragma unroll
        for(int fn=0;fn<4;fn++)
          acc[fm][fn] = __builtin_amdgcn_mfma_f32_16x16x32_bf16(a[fm], b[fn], acc[fm][fn], 0,0,0);
    }
  }
  #pragma unroll
  for(int fm=0;fm<4;fm++){
    int oc0 = fm*16 + ks*4;
    #pragma unroll
    for(int fn=0;fn<4;fn++){
      int pxt = px0 + w_*64 + fn*16 + l15;
      union{ uint2 u; bf16 h[4]; } pk;
      #pragma unroll
      for(int j=0;j<4;j++) pk.h[j]=__float2bfloat16(fmaxf(acc[fm][fn][j]+bias[oc0+j],0.f));
      *(uint2*)(outN + (size_t)pxt*64 + oc0) = pk.u;
    }
  }
}

// ---------------- routing select -> featN (96ch) + fused timep tail blocks ----------------
__global__ void k_routeT(const bf16* __restrict__ xs, const bf16* __restrict__ xm,
                         const bf16* __restrict__ xh, const float* __restrict__ xseg,
                         const float* __restrict__ scalp, const float* __restrict__ tl,
                         const float* __restrict__ tr, bf16* __restrict__ featN,
                         int nroute, float* __restrict__ dtp){
  __shared__ float sh[256];
  int bidx = blockIdx.x;
  float tl0 = tl[0], tr0 = tr[0], thr = tl0+tr0;
  if(bidx >= nroute){
    int b = bidx - nroute, t = threadIdx.x;
    float v=0.f;
    if(t<25){
      float sz=scalp[b*25+t];
      v = (sz>thr) ? 1e-4f*(sz-thr) : ((sz>=tl0 && sz<=thr) ? 2e-4f*tr0 : 3e-4f*(tl0-sz));
    }
    sh[t]=v; __syncthreads();
    for(int o=128;o>0;o>>=1){ if(t<o) sh[t]+=sh[t+o]; __syncthreads(); }
    if(t==0) dtp[b]=sh[0]*(1.f/25.f);
    return;
  }
  int idx = bidx*256+threadIdx.x;
  int c = idx%12; int px = idx/12;
  int b = px/25600; int rem = px - b*25600;
  int y = rem/160, xx = rem - y*160;
  int n = b*25 + (y>>5)*5 + (xx>>5);
  float sz = scalp[n];
  const bf16* src = (sz>thr) ? xs : ((sz>=tl0 && sz<=thr) ? xm : xh);
  uint4 v = make_uint4(0,0,0,0);
  if(c < 8){
    v = *(const uint4*)(src + ((size_t)n*1024 + ((y&31)<<5) + (xx&31))*64 + c*8);
  } else if(c == 8){
    union{ uint4 q; bf16 h[8]; } pk;
    pk.q = make_uint4(0,0,0,0);
    pk.h[0]=__float2bfloat16(xseg[(b*3+0)*25600 + rem]-MEAN0);
    pk.h[1]=__float2bfloat16(xseg[(b*3+1)*25600 + rem]-MEAN1);
    pk.h[2]=__float2bfloat16(xseg[(b*3+2)*25600 + rem]-MEAN2);
    v = pk.q;
  }
  *(uint4*)(featN + (size_t)px*96 + c*8) = v;
}

// ---------------- MARM MFMA: 96ch NHWC bf16 conv3x3 -> 64ch NHWC bf16, relu ----------------
__global__ __launch_bounds__(256,2) void k_marmM(const bf16* __restrict__ featN,
                        const bf16* __restrict__ wpm, const float* __restrict__ bias,
                        bf16* __restrict__ outN){
  __shared__ __align__(16) __bf16 sB[12*340*8];  // 65280 B
  __shared__ __align__(16) __bf16 sA[12*64*8];   // 12288 B
  int bid = blockIdx.x;
  int img = bid/100; int t_ = bid - img*100;
  int y0 = (t_/5)*8, x0 = (t_%5)*32;
  int tid = threadIdx.x;
  const bf16* ib = featN + (size_t)img*25600*96;
  for(int cid=tid; cid<4080; cid+=256){
    int icg = cid/340, p = cid - icg*340;
    int r = p/34, cc = p - r*34;
    int gy = y0-1+r, gx = x0-1+cc;
    float4 v = {0.f,0.f,0.f,0.f};
    if((unsigned)gy<160u && (unsigned)gx<160u)
      v = *(const float4*)(ib + (size_t)(gy*160+gx)*96 + icg*8);
    *(float4*)(&sB[(size_t)(icg*340+p)*8]) = v;
  }
  for(int cid=tid; cid<768; cid+=256)
    *(float4*)(&sA[(size_t)cid*8]) = ((const float4*)wpm)[cid];
  __syncthreads();
  int w_ = tid>>6, l = tid&63;
  int ks = l>>4, l15 = l&15;
  f32x4 acc[4][4];
  #pragma unroll
  for(int i=0;i<4;i++)
    #pragma unroll
    for(int j=0;j<4;j++) acc[i][j]=(f32x4){0.f,0.f,0.f,0.f};
  int pr[4], pc[4];
  #pragma unroll
  for(int fn=0;fn<4;fn++){ int npx = w_*64+fn*16+l15; pr[fn]=npx>>5; pc[fn]=npx&31; }
  float4 pre[3];
  for(int tap=0;tap<9;tap++){
    if(tap<8){
      #pragma unroll
      for(int k=0;k<3;k++) pre[k] = ((const float4*)wpm)[(tap+1)*768 + k*256 + tid];
    }
    int ty=tap/3, tx=tap-ty*3;
    #pragma unroll
    for(int kk=0;kk<3;kk++){
      int tc = kk*4+ks;
      bf16x8 a[4], b[4];
      #pragma unroll
      for(int fm=0;fm<4;fm++) a[fm] = *(const bf16x8*)(&sA[(size_t)(tc*64 + fm*16+l15)*8]);
      #pragma unroll
      for(int fn=0;fn<4;fn++)
        b[fn] = *(const bf16x8*)(&sB[(size_t)(tc*340 + (pr[fn]+ty)*34 + pc[fn]+tx)*8]);
      #pragma unroll
      for(int fm=0;fm<4;fm++)
        #pragma unroll
        for(int fn=0;fn<4;fn++)
          acc[fm][fn] = __builtin_amdgcn_mfma_f32_16x16x32_bf16(a[fm], b[fn], acc[fm][fn], 0,0,0);
    }
    if(tap<8){
      __syncthreads();
      #pragma unroll
      for(int k=0;k<3;k++) ((float4*)sA)[k*256+tid] = pre[k];
      __syncthreads();
    }
  }
  bf16* ob = outN + (size_t)img*25600*64;
  #pragma unroll
  for(int fm=0;fm<4;fm++){
    int oc0 = fm*16 + ks*4;
    #pragma unroll
    for(int fn=0;fn<4;fn++){
      int px = (y0+pr[fn])*160 + x0+pc[fn];
      union{ uint2 u; bf16 h[4]; } pk;
      #pragma unroll
      for(int j=0;j<4;j++) pk.h[j]=__float2bfloat16(fmaxf(acc[fm][fn][j]+bias[oc0+j],0.f));
      *(uint2*)(ob + (size_t)px*64 + oc0) = pk.u;
    }
  }
}

// ---------------- MFMA up-conv v5 (reverted, occupancy 4): 64->256 conv3x3 + ps(2) + relu ----------------
// tile 4x16 px, all 256 oc (4 waves); A 12-wide pinned bursts; epilogue 2 x 16KB phases.
template<int H, int W>
__global__ __launch_bounds__(256,4) void k_convup(const bf16* __restrict__ in,
                        bf16* __restrict__ o0, bf16* __restrict__ o1,
                        const bf16* __restrict__ wp, const float* __restrict__ bias){
  constexpr int TXC = W/16, TPB = (H/4)*TXC;
  __shared__ __align__(16) char smem[16384];
  __bf16* sB = (__bf16*)smem;
  int bid = blockIdx.x;
  int img = bid/TPB; int t_ = bid - img*TPB;
  int y0 = (t_/TXC)*4, x0 = (t_%TXC)*16;
  int tid = threadIdx.x;
  const bf16* ib = in + (size_t)img*H*W*64;
  for(int cid=tid; cid<864; cid+=256){
    int p = cid>>3, tt = cid&7;
    int r = p/18, cc = p - r*18;
    int gy = y0-1+r, gx = x0-1+cc;
    float4 v = {0.f,0.f,0.f,0.f};
    if((unsigned)gy<(unsigned)H && (unsigned)gx<(unsigned)W)
      v = *(const float4*)(ib + ((size_t)(gy*W+gx)*64 + tt*8));
    *(float4*)(&sB[(size_t)(p*8 + (tt^(p&7)))*8]) = v;
  }
  __syncthreads();
  int w_ = tid>>6, l = tid&63;
  int ks = l>>4, l15 = l&15;
  f32x4 acc[4][4];
  #pragma unroll
  for(int i=0;i<4;i++)
    #pragma unroll
    for(int j=0;j<4;j++) acc[i][j]=(f32x4){0.f,0.f,0.f,0.f};
  const bf16* wpb = wp + ((size_t)w_*64 + l15)*8;
  #pragma unroll
  for(int kk=0;kk<2;kk++){
    int tc = kk*4+ks;
    #pragma unroll
    for(int tr=0;tr<3;tr++){
      bf16x8 afr[3][4];
      #pragma unroll
      for(int tx=0;tx<3;tx++)
        #pragma unroll
        for(int fm=0;fm<4;fm++)
          afr[tx][fm] = *(const bf16x8*)(wpb + ((size_t)(((tr*3+tx)*8+tc)*256) + fm*16)*8);
      #pragma unroll
      for(int tx=0;tx<3;tx++)
        #pragma unroll
        for(int fm=0;fm<4;fm++)
          asm volatile("" : "+v"(afr[tx][fm]));
      #pragma unroll
      for(int tx=0;tx<3;tx++){
        bf16x8 b[4];
        #pragma unroll
        for(int fn=0;fn<4;fn++){
          int p = (fn+tr)*18 + l15+tx;
          b[fn] = *(const bf16x8*)(&sB[(size_t)(p*8 + (tc^(p&7)))*8]);
        }
        #pragma unroll
        for(int fm=0;fm<4;fm++)
          #pragma unroll
          for(int fn=0;fn<4;fn++)
            acc[fm][fn] = __builtin_amdgcn_mfma_f32_16x16x32_bf16(afr[tx][fm], b[fn], acc[fm][fn], 0,0,0);
      }
    }
  }
  bf16* ob = ((img&1) ? o1 : o0) + (size_t)(img>>1)*((size_t)8*H*W*64);
  const int W2 = 2*W;
  char* oT = smem;
  #pragma unroll
  for(int h=0;h<2;h++){
    __syncthreads();
    #pragma unroll
    for(int fm=0;fm<4;fm++){
      int co = w_*16 + fm*4 + ks;
      #pragma unroll
      for(int j=0;j<4;j++){
        float bsv = bias[w_*64 + fm*16 + ks*4 + j];
        int r1=(j>>1)&1, r2=j&1;
        #pragma unroll
        for(int ff=0;ff<2;ff++){
          int fn = 2*h+ff;
          int opx = (2*ff+r1)*32 + 2*l15+r2;
          float v = fmaxf(acc[fm][fn][j]+bsv, 0.f);
          int sl = (co>>3) ^ ((opx>>1)&7);
          *(bf16*)(oT + opx*128 + sl*16 + (co&7)*2) = __float2bfloat16(v);
        }
      }
    }
    __syncthreads();
    #pragma unroll
    for(int k=0;k<4;k++){
      int cid = k*256 + tid;
      int p = cid>>3, lq = cid&7;
      int sl = lq ^ ((p>>1)&7);
      uint4 v = *(const uint4*)(oT + p*128 + sl*16);
      int Y = 2*y0 + 4*h + (p>>5), X = 2*x0 + (p&31);
      *(uint4*)(ob + ((size_t)Y*W2 + X)*64 + lq*8) = v;
    }
  }
}

// ---------------- final conv MFMA (2 images per dispatch): writes y, xcropia, xoutputa ----------------
__global__ __launch_bounds__(256,3) void k_upcM(const bf16* __restrict__ i0,
                        const bf16* __restrict__ i1, const bf16* __restrict__ wpu,
                        const float* __restrict__ bias, const float* __restrict__ scal,
                        float* __restrict__ dout, int b0){
  __shared__ __align__(16) __bf16 sB[396*64];   // 50688 B
  int tid = threadIdx.x;
  int img = blockIdx.x/1600; int t_ = blockIdx.x - img*1600;
  const bf16* in = img ? i1 : i0;
  int b = b0 + img;
  int by0 = (t_/10)*4, bx0 = (t_%10)*64;
  for(int cid=tid; cid<3168; cid+=256){
    int px = cid>>3, c = cid&7;
    int hr = px/66, hc = px - hr*66;
    int gy = by0-1+hr, gx = bx0-1+hc;
    float4 v = {0.f,0.f,0.f,0.f};
    if((unsigned)gy<640u && (unsigned)gx<640u)
      v = *(const float4*)(in + ((size_t)(gy*640+gx))*64 + c*8);
    int slot = c ^ (px&7);
    *(float4*)(&sB[(size_t)px*64 + slot*8]) = v;
  }
  int w_ = tid>>6, l = tid&63;
  int ks = l>>4, l15 = l&15;
  bf16x8 afr[9][2];
  #pragma unroll
  for(int tap=0;tap<9;tap++)
    #pragma unroll
    for(int kk=0;kk<2;kk++)
      afr[tap][kk] = *(const bf16x8*)(wpu + (size_t)((tap*8 + kk*4+ks)*16 + l15)*8);
  __syncthreads();
  f32x4 acc[4];
  #pragma unroll
  for(int fn=0;fn<4;fn++) acc[fn]=(f32x4){0.f,0.f,0.f,0.f};
  int r = w_;
  int cxc[4];
  #pragma unroll
  for(int fn=0;fn<4;fn++) cxc[fn]=fn*16+l15;
  for(int tap=0;tap<9;tap++){
    int ty=tap/3, tx=tap-ty*3;
    #pragma unroll
    for(int kk=0;kk<2;kk++){
      int tc = kk*4+ks;
      #pragma unroll
      for(int fn=0;fn<4;fn++){
        int ph = (r+ty)*66 + cxc[fn]+tx;
        int slot = tc ^ (ph&7);
        bf16x8 bb = *(const bf16x8*)(&sB[(size_t)ph*64 + slot*8]);
        acc[fn] = __builtin_amdgcn_mfma_f32_16x16x32_bf16(afr[tap][kk], bb, acc[fn], 0,0,0);
      }
    }
  }
  if(ks==0){
    float c0=bias[0]+MEAN0, c1=bias[1]+MEAN1, c2=bias[2]+MEAN2;
    int gy = by0 + r;
    size_t yb=(size_t)b*3*409600;
    #pragma unroll
    for(int fn=0;fn<4;fn++){
      int gx = bx0 + cxc[fn];
      float a0=acc[fn][0]+c0, a1=acc[fn][1]+c1, a2=acc[fn][2]+c2;
      int n=b*25+(gy>>7)*5+(gx>>7);
      float sv=scal[128+n];
      size_t pidx=(size_t)gy*640+gx;
      dout[yb+pidx]=a0; dout[yb+409600+pidx]=a1; dout[yb+819200+pidx]=a2;
      dout[4915204 + (size_t)b*409600 + pidx]=sv;
      size_t xa=6553604+yb;
      dout[xa+pidx]=a0*sv; dout[xa+409600+pidx]=a1*sv; dout[xa+819200+pidx]=a2*sv;
    }
  }
}

extern "C" void kernel_launch(void* const* d_in, const int* in_sizes, int n_in,
                              void* d_out, int out_size, void* d_ws, size_t ws_size,
                              hipStream_t stream){
  const float* x     =(const float*)d_in[0];
  const float* tl    =(const float*)d_in[1];
  const float* tr    =(const float*)d_in[2];
  const float* iicm_w=(const float*)d_in[3];
  const float* iicm_b=(const float*)d_in[4];
  const float* conv4_w=(const float*)d_in[5];
  const float* conv4_b=(const float*)d_in[6];
  const float* b1_w1 =(const float*)d_in[7];  const float* b1_b1=(const float*)d_in[8];
  const float* b1_w2 =(const float*)d_in[9];  const float* b1_b2=(const float*)d_in[10];
  const float* c1_w  =(const float*)d_in[11]; const float* c1_b =(const float*)d_in[12];
  const float* b2_w1 =(const float*)d_in[13]; const float* b2_b1=(const float*)d_in[14];
  const float* b2_w2 =(const float*)d_in[15]; const float* b2_b2=(const float*)d_in[16];
  const float* c2_w  =(const float*)d_in[17]; const float* c2_b =(const float*)d_in[18];
  const float* b3_w1 =(const float*)d_in[19]; const float* b3_b1=(const float*)d_in[20];
  const float* b3_w2 =(const float*)d_in[21]; const float* b3_b2=(const float*)d_in[22];
  const float* c3_w  =(const float*)d_in[23]; const float* c3_b =(const float*)d_in[24];
  const float* marm_w=(const float*)d_in[25]; const float* marm_b=(const float*)d_in[26];
  const float* up1_w =(const float*)d_in[27]; const float* up1_b=(const float*)d_in[28];
  const float* up2_w =(const float*)d_in[29]; const float* up2_b=(const float*)d_in[30];
  const float* upc_w =(const float*)d_in[31]; const float* upc_b=(const float*)d_in[32];

  char* base = (char*)d_ws;
  float* out =(float*)d_out;
  float* scal=(float*)base;
  float* partial=(float*)(base+1024);

  const int SEG = (ws_size >= 188417024ull) ? 4 : 1;
  const int NP  = SEG*25;
  const int NPix= NP*1024;

  const size_t SZB = (size_t)NP*131072;
  char* bufs = base + 8192;
  bf16* fN   = (bf16*)(bufs + 0*SZB);
  bf16* tmpN = (bf16*)(bufs + 1*SZB);
  bf16* xsN  = (bf16*)(bufs + 2*SZB);
  bf16* b1oN = (bf16*)(bufs + 3*SZB);
  bf16* b2oN = (bf16*)(bufs + 4*SZB);
  bf16* xmN  = (bf16*)(bufs + 5*SZB);
  bf16* b3oN = (bf16*)(bufs + 6*SZB);
  bf16* xhN  = (bf16*)(bufs + 7*SZB);
  bf16* featN= (bf16*)(bufs + 0*SZB);
  bf16* marmN= (bf16*)(bufs + 2*SZB);
  bf16* ps1  = (bf16*)(bufs + 4*SZB);
  bf16* ps2a = (bf16*)(bufs + 8*SZB);
  bf16* ps2b = (bf16*)(bufs + 0*SZB);
  char* packsp = bufs + 8*SZB + 52428800;
  bf16* wpc  = (bf16*)packsp;                       // 36864
  bf16* wp1  = wpc + 36864;                         // 147456
  bf16* wp2  = wp1 + 147456;                        // 147456
  bf16* wpm  = wp2 + 147456;                        // 55296
  bf16* wpu  = wpm + 55296;                         // 9216
  bf16* wpg2 = wpu + 9216;                          // 61440
  bf16* wp4  = wpg2 + 61440;                        // 10240
  bf16* f16N = wp4 + 10240;                         // NP*16384 bf16

  k_wpack<<<1829,256,0,stream>>>(c1_w,c2_w,c3_w, up1_w,up2_w, marm_w, upc_w,
                                 b1_w1,b1_w2,b2_w1,b2_w2,b3_w1,b3_w2, conv4_w, wpc);

  for(int b0=0;b0<4;b0+=SEG){
    int p0 = b0*25;
    const float* xseg = x + (size_t)b0*3*25600;
    float* scalp = scal + p0;

    k_iicm <<<NP*4,  256,0,stream>>>(xseg, iicm_w, iicm_b, f16N, partial);
    k_conv4M<<<NP*8+NP, 128,0,stream>>>(f16N, wp4, conv4_b, fN, partial, scalp, NP*8);
    // block 1
    k_gconvM<<<NP*8, 128,0,stream>>>(fN,   wpg2,         b1_b1, (const bf16*)0, tmpN, 1);
    k_gconvM<<<NP*8, 128,0,stream>>>(tmpN, wpg2+10240,   b1_b2, fN,             b1oN, 0);
    k_1x1M <<<NP*4,  256,0,stream>>>(fN, b1oN, (const bf16*)0, (const bf16*)0, 2, wpc, c1_b, xsN);
    // block 2
    k_gconvM<<<NP*8, 128,0,stream>>>(xsN,  wpg2+2*10240, b2_b1, (const bf16*)0, tmpN, 1);
    k_gconvM<<<NP*8, 128,0,stream>>>(tmpN, wpg2+3*10240, b2_b2, xsN,            b2oN, 0);
    k_1x1M <<<NP*4,  256,0,stream>>>(fN, b1oN, b2oN, (const bf16*)0, 3, wpc+8192, c2_b, xmN);
    // block 3
    k_gconvM<<<NP*8, 128,0,stream>>>(xmN,  wpg2+4*10240, b3_b1, (const bf16*)0, tmpN, 1);
    k_gconvM<<<NP*8, 128,0,stream>>>(tmpN, wpg2+5*10240, b3_b2, xmN,            b3oN, 0);
    k_1x1M <<<NP*4,  256,0,stream>>>(fN, b1oN, b2oN, b3oN, 4, wpc+20480, c3_b, xhN);
    // routing -> featN (96ch NHWC) + fused timep
    k_routeT<<<NP*48+SEG,256,0,stream>>>(xsN, xmN, xhN, xseg, scalp, tl, tr, featN,
                                         NP*48, out + 4915200 + b0);
    // MARM + upsample chain
    k_marmM<<<SEG*100, 256,0,stream>>>(featN, wpm, marm_b, marmN);
    k_convup<160,160><<<SEG*400, 256,0,stream>>>(marmN, ps1, ps1 + 6553600, wp1, up1_b);
    for(int i=0;i<SEG;i+=2){
      int ni = (SEG-i>=2)?2:1;
      k_convup<320,320><<<ni*1600, 256,0,stream>>>(ps1 + (size_t)i*6553600, ps2a, ps2b, wp2, up2_b);
      k_upcM<<<ni*1600,256,0,stream>>>(ps2a, ps2b, wpu, upc_b, scal, out, b0+i);
    }
  }
}

// Round 14
// 459.970 us; speedup vs baseline: 1.7980x; 1.7980x over previous
//
#include <hip/hip_runtime.h>
#include <hip/hip_bf16.h>

typedef __hip_bfloat16 bf16;
typedef __bf16 bf16x8 __attribute__((ext_vector_type(8)));
typedef float f32x4 __attribute__((ext_vector_type(4)));

#define MEAN0 0.4488f
#define MEAN1 0.4371f
#define MEAN2 0.4040f

// ---------------- IICM: 3->12 conv3x3 per 32x32 patch, relu -> NHWC-16 bf16 + partials (|f|, v, v^2) ----------------
__global__ void k_iicm(const float* __restrict__ x, const float* __restrict__ w,
                       const float* __restrict__ bias, bf16* __restrict__ outN16,
                       float* __restrict__ partial){
  __shared__ __align__(16) float ws_[324];   // [tap27][oc12]
  __shared__ float bs[12];
  __shared__ float sh[256];
  for(int k=threadIdx.x;k<324;k+=256){ int t0=k/12, kk=k%12; ws_[k]=w[kk*27+t0]; }
  if(threadIdx.x<12) bs[threadIdx.x]=bias[threadIdx.x];
  __syncthreads();
  int idx = blockIdx.x*256+threadIdx.x;
  int pix = idx & 1023, n = idx >> 10;
  int i = pix>>5, j = pix&31;
  int pw = n%5, ph=(n/5)%5, bb=n/25;
  float acc[12];
  #pragma unroll
  for(int k=0;k<12;k++) acc[k]=bs[k];
  #pragma unroll
  for(int c=0;c<3;c++){
    const float* xb = x + ((bb*3+c)*160 + ph*32)*160 + pw*32;
    float mc = (c==0)?MEAN0:((c==1)?MEAN1:MEAN2);
    #pragma unroll
    for(int dy=-1;dy<=1;dy++){
      int ii=i+dy; if((unsigned)ii>=32u) continue;
      #pragma unroll
      for(int dx=-1;dx<=1;dx++){
        int jj=j+dx; if((unsigned)jj>=32u) continue;
        float v = xb[ii*160+jj]-mc;
        int t0 = c*9+(dy+1)*3+(dx+1);
        const float4* wv = (const float4*)&ws_[t0*12];
        float4 w0=wv[0], w1=wv[1], w2=wv[2];
        acc[0]+=v*w0.x; acc[1]+=v*w0.y; acc[2]+=v*w0.z; acc[3]+=v*w0.w;
        acc[4]+=v*w1.x; acc[5]+=v*w1.y; acc[6]+=v*w1.z; acc[7]+=v*w1.w;
        acc[8]+=v*w2.x; acc[9]+=v*w2.y; acc[10]+=v*w2.z; acc[11]+=v*w2.w;
      }
    }
  }
  float s=0.f;
  #pragma unroll
  for(int k=0;k<12;k++){ acc[k]=fmaxf(acc[k],0.f); s+=acc[k]; }
  union{ float4 v; bf16 h[8]; } p0, p1;
  #pragma unroll
  for(int k=0;k<8;k++) p0.h[k]=__float2bfloat16(acc[k]);
  #pragma unroll
  for(int k=0;k<4;k++) p1.h[k]=__float2bfloat16(acc[8+k]);
  #pragma unroll
  for(int k=4;k<8;k++) p1.h[k]=__float2bfloat16(0.f);
  bf16* o16 = outN16 + (size_t)(n*1024+pix)*16;
  *(float4*)o16 = p0.v;
  *(float4*)(o16+8) = p1.v;
  const float* xb0 = x + ((bb*3)*160 + ph*32)*160 + pw*32;
  float v0 = xb0[i*160+j]-MEAN0;
  sh[threadIdx.x]=s; __syncthreads();
  for(int o=128;o>0;o>>=1){ if(threadIdx.x<o) sh[threadIdx.x]+=sh[threadIdx.x+o]; __syncthreads(); }
  if(threadIdx.x==0) partial[blockIdx.x*4+0]=sh[0];
  __syncthreads();
  sh[threadIdx.x]=v0; __syncthreads();
  for(int o=128;o>0;o>>=1){ if(threadIdx.x<o) sh[threadIdx.x]+=sh[threadIdx.x+o]; __syncthreads(); }
  if(threadIdx.x==0) partial[blockIdx.x*4+1]=sh[0];
  __syncthreads();
  sh[threadIdx.x]=v0*v0; __syncthreads();
  for(int o=128;o>0;o>>=1){ if(threadIdx.x<o) sh[threadIdx.x]+=sh[threadIdx.x+o]; __syncthreads(); }
  if(threadIdx.x==0) partial[blockIdx.x*4+2]=sh[0];
}

// ---------------- unified weight pack (all convs) ----------------
__global__ void k_wpack(const float* __restrict__ c1_w, const float* __restrict__ c2_w,
                        const float* __restrict__ c3_w, const float* __restrict__ up1_w,
                        const float* __restrict__ up2_w, const float* __restrict__ marm_w,
                        const float* __restrict__ upc_w, const float* __restrict__ b1_w1,
                        const float* __restrict__ b1_w2, const float* __restrict__ b2_w1,
                        const float* __restrict__ b2_w2, const float* __restrict__ b3_w1,
                        const float* __restrict__ b3_w2, const float* __restrict__ conv4_w,
                        bf16* __restrict__ packs){
  int idx = blockIdx.x*256+threadIdx.x;
  if(idx>=467968) return;
  float v;
  if(idx<36864){
    const float* w; int Cin, base;
    if(idx<8192){ w=c1_w; Cin=128; base=0; }
    else if(idx<20480){ w=c2_w; Cin=192; base=8192; }
    else { w=c3_w; Cin=256; base=20480; }
    int r=idx-base; int g=r>>9, oc=(r>>3)&63, j=r&7;
    v = w[oc*Cin + g*8 + j];
  } else if(idx<331776){
    int r0=idx-36864;
    int conv=r0/147456; int r=r0-conv*147456;
    int tap=r>>14; int r2=r&16383;
    int s=(r2>>11)&7, oc=(r2>>3)&255, j=r2&7;
    int ic=s*8+j;
    const float* w = conv? up2_w : up1_w;
    v = w[oc*576 + ic*9 + tap];
  } else if(idx<387072){
    int r=idx-331776;
    int tap=r/6144; int rr=r-tap*6144;
    int icg=rr>>9, oc=(rr>>3)&63, j=rr&7;
    int ic=icg*8+j;
    v = 0.f;
    if(ic<64)      v = marm_w[oc*603 + (3+ic)*9 + tap];
    else if(ic<67) v = marm_w[oc*603 + (ic-64)*9 + tap];
  } else if(idx<396288){
    int r=idx-387072;
    int tap=r>>10; int rr=r&1023;
    int tc=rr>>7, oc=(rr>>3)&15, j=rr&7;
    int ic=tc*8+j;
    v = (oc<3) ? upc_w[oc*576 + ic*9 + tap] : 0.f;
  } else if(idx<457728){
    int r=idx-396288;
    int conv=r/10240; int rr=r-conv*10240;
    int tp=rr/2048; int r2=rr&2047;
    int oc=r2>>5; int k=r2&31;
    int ks=k>>3, e=k&7;
    int tap=2*tp+(ks>>1);
    int il=(ks&1)*8+e;
    const float* w = (conv==0)?b1_w1:(conv==1)?b1_w2:(conv==2)?b2_w1:(conv==3)?b2_w2:(conv==4)?b3_w1:b3_w2;
    v = (tap<9) ? w[oc*144 + il*9 + tap] : 0.f;
  } else {
    int r=idx-457728;
    int tp=r/2048; int r2=r&2047;
    int oc=r2>>5; int k=r2&31;
    int ks=k>>3, e=k&7;
    int tap=2*tp+(ks>>1);
    int ic=(ks&1)*8+e;
    v = (tap<9 && ic<12) ? conv4_w[oc*108 + ic*9 + tap] : 0.f;
  }
  packs[idx]=__float2bfloat16(v);
}

// ---------------- conv4 MFMA (tap-packed) + scal-finish tail blocks ----------------
__global__ __launch_bounds__(128,3) void k_conv4M(const bf16* __restrict__ in,
                        const bf16* __restrict__ wp4, const float* __restrict__ bias,
                        bf16* __restrict__ outN, const float* __restrict__ partial,
                        float* __restrict__ scalp, int nconv){
  int tid=threadIdx.x, bid=blockIdx.x;
  if(bid >= nconv){
    if(tid==0){
      int n = bid - nconv;
      float s=0.f, sm=0.f, sq=0.f;
      #pragma unroll
      for(int q=0;q<4;q++){
        s  += partial[(n*4+q)*4+0];
        sm += partial[(n*4+q)*4+1];
        sq += partial[(n*4+q)*4+2];
      }
      scalp[n] = s*(1.f/12288.f);
      float smean = sm*(1.f/1024.f);
      float var = sq*(1.f/1024.f) - smean*smean;
      scalp[128+n] = sqrtf(fmaxf(var,0.f));
    }
    return;
  }
  __shared__ __align__(16) __bf16 sB[204*2*8];   // 6528 B
  int n=bid>>3, tile=bid&7, y0=tile*4;
  const bf16* ib = in + (size_t)n*16384;
  for(int cid=tid; cid<408; cid+=128){
    int p=cid>>1, c=cid&1;
    int r=p/34, cc=p-r*34;
    int gy=y0-1+r, gx=cc-1;
    float4 v={0.f,0.f,0.f,0.f};
    if((unsigned)gy<32u && (unsigned)gx<32u)
      v = *(const float4*)(ib + (size_t)((gy<<5)+gx)*16 + c*8);
    *(float4*)(&sB[(size_t)(p*2 + (c^(p&1)))*8]) = v;
  }
  __syncthreads();
  int w_=tid>>6, l=tid&63;
  int ks=l>>4, l15=l&15;
  int h=ks>>1, cb=ks&1;
  f32x4 acc[4][4];
  #pragma unroll
  for(int i=0;i<4;i++)
    #pragma unroll
    for(int j=0;j<4;j++) acc[i][j]=(f32x4){0.f,0.f,0.f,0.f};
  int pr[4], pc[4];
  #pragma unroll
  for(int fn=0;fn<4;fn++){ int npx=w_*64+fn*16+l15; pr[fn]=npx>>5; pc[fn]=npx&31; }
  #pragma unroll
  for(int tp=0;tp<5;tp++){
    bf16x8 afr[4];
    #pragma unroll
    for(int fm=0;fm<4;fm++)
      afr[fm] = *(const bf16x8*)(wp4 + (((size_t)(tp*64 + fm*16 + l15))*4 + ks)*8);
    #pragma unroll
    for(int fm=0;fm<4;fm++) asm volatile("" : "+v"(afr[fm]));
    const int t0=2*tp, t1=(2*tp+1>8)?8:(2*tp+1);
    int ty = h ? (t1/3) : (t0/3);
    int tx = h ? (t1%3) : (t0%3);
    #pragma unroll
    for(int fn=0;fn<4;fn++){
      int p = (pr[fn]+ty)*34 + pc[fn]+tx;
      bf16x8 b = *(const bf16x8*)(&sB[(size_t)(p*2 + (cb^(p&1)))*8]);
      #pragma unroll
      for(int fm=0;fm<4;fm++)
        acc[fm][fn] = __builtin_amdgcn_mfma_f32_16x16x32_bf16(afr[fm], b, acc[fm][fn], 0,0,0);
    }
  }
  bf16* ob = outN + (size_t)n*65536;
  #pragma unroll
  for(int fm=0;fm<4;fm++){
    int oc0 = fm*16 + ks*4;
    #pragma unroll
    for(int fn=0;fn<4;fn++){
      int pxl = (y0+pr[fn])*32 + pc[fn];
      union{ uint2 u; bf16 hh[4]; } pk;
      #pragma unroll
      for(int j=0;j<4;j++) pk.hh[j]=__float2bfloat16(acc[fm][fn][j]+bias[oc0+j]);
      *(uint2*)(ob + (size_t)pxl*64 + oc0) = pk.u;
    }
  }
}

// ---------------- grouped MFMA conv (tap-packed, proper groups): 64->64 conv3x3 per patch ----------------
__global__ __launch_bounds__(128,3) void k_gconvM(const bf16* __restrict__ in,
                        const bf16* __restrict__ wg, const float* __restrict__ bias,
                        const bf16* __restrict__ resid, bf16* __restrict__ out, int do_relu){
  __shared__ __align__(16) __bf16 sB[204*8*8];   // 26112 B
  int tid = threadIdx.x;
  int bid = blockIdx.x;
  int n = bid>>3, tile = bid&7;
  int y0 = tile*4;
  const bf16* ib = in + (size_t)n*65536;
  for(int cid=tid; cid<1632; cid+=128){
    int p = cid>>3, s = cid&7;
    int r = p/34, c = p - r*34;
    int gy = y0-1+r, gx = c-1;
    float4 v = {0.f,0.f,0.f,0.f};
    if((unsigned)gy<32u && (unsigned)gx<32u)
      v = *(const float4*)(ib + (size_t)((gy<<5)+gx)*64 + s*8);
    *(float4*)(&sB[(size_t)(p*8 + (s^(p&7)))*8]) = v;
  }
  __syncthreads();
  int w_ = tid>>6, l = tid&63;
  int ks = l>>4, l15 = l&15;
  int h = ks>>1, cb = ks&1;
  f32x4 acc[4][4];
  #pragma unroll
  for(int i=0;i<4;i++)
    #pragma unroll
    for(int j=0;j<4;j++) acc[i][j]=(f32x4){0.f,0.f,0.f,0.f};
  int pr[4], pc[4];
  #pragma unroll
  for(int fn=0;fn<4;fn++){ int npx = w_*64+fn*16+l15; pr[fn]=npx>>5; pc[fn]=npx&31; }
  #pragma unroll
  for(int tp=0;tp<5;tp++){
    bf16x8 afr[4];
    #pragma unroll
    for(int fm=0;fm<4;fm++)
      afr[fm] = *(const bf16x8*)(wg + (((size_t)(tp*64 + fm*16 + l15))*4 + ks)*8);
    #pragma unroll
    for(int fm=0;fm<4;fm++) asm volatile("" : "+v"(afr[fm]));
    const int t0=2*tp, t1=(2*tp+1>8)?8:(2*tp+1);
    int ty = h ? (t1/3) : (t0/3);
    int tx = h ? (t1%3) : (t0%3);
    #pragma unroll
    for(int fn=0;fn<4;fn++){
      int p = (pr[fn]+ty)*34 + pc[fn]+tx;
      int pb = p*8;
      #pragma unroll
      for(int fm=0;fm<4;fm++){
        int c = fm*2 + cb;
        bf16x8 b = *(const bf16x8*)(&sB[(size_t)(pb + (c^(p&7)))*8]);
        acc[fm][fn] = __builtin_amdgcn_mfma_f32_16x16x32_bf16(afr[fm], b, acc[fm][fn], 0,0,0);
      }
    }
  }
  bf16* ob = out + (size_t)n*65536;
  const bf16* rb = resid ? resid + (size_t)n*65536 : (const bf16*)0;
  #pragma unroll
  for(int fm=0;fm<4;fm++){
    int oc0 = fm*16 + ks*4;
    #pragma unroll
    for(int fn=0;fn<4;fn++){
      int pxl = (y0+pr[fn])*32 + pc[fn];
      float v[4];
      #pragma unroll
      for(int j=0;j<4;j++){
        float t = acc[fm][fn][j] + bias[oc0+j];
        if(do_relu) t = fmaxf(t,0.f);
        v[j]=t;
      }
      if(rb){
        union{ uint2 u; bf16 h[4]; } ru;
        ru.u = *(const uint2*)(rb + (size_t)pxl*64 + oc0);
        #pragma unroll
        for(int j=0;j<4;j++) v[j] += __bfloat162float(ru.h[j]);
      }
      union{ uint2 u; bf16 h[4]; } pk;
      #pragma unroll
      for(int j=0;j<4;j++) pk.h[j]=__float2bfloat16(v[j]);
      *(uint2*)(ob + (size_t)pxl*64 + oc0) = pk.u;
    }
  }
}

// ---------------- MFMA 1x1 conv (pure GEMM): A from L2, B staged; relu ----------------
__global__ __launch_bounds__(256,4) void k_1x1M(const bf16* __restrict__ s0,
                        const bf16* __restrict__ s1, const bf16* __restrict__ s2,
                        const bf16* __restrict__ s3, int ns,
                        const bf16* __restrict__ wpk, const float* __restrict__ bias,
                        bf16* __restrict__ outN){
  __shared__ __align__(16) __bf16 sB[8*256*8];   // 32768 B
  int tid = threadIdx.x;
  int px0 = blockIdx.x*256;
  int w_ = tid>>6, l = tid&63;
  int ks = l>>4, l15 = l&15;
  f32x4 acc[4][4];
  #pragma unroll
  for(int i=0;i<4;i++)
    #pragma unroll
    for(int j=0;j<4;j++) acc[i][j]=(f32x4){0.f,0.f,0.f,0.f};
  const bf16* srcs[4]={s0,s1,s2,s3};
  for(int s=0;s<ns;s++){
    __syncthreads();
    const bf16* sp = srcs[s];
    #pragma unroll
    for(int it=0;it<8;it++){
      *(float4*)(&sB[(size_t)(it*256+tid)*8]) = *(const float4*)(sp + (size_t)(px0+tid)*64 + it*8);
    }
    __syncthreads();
    #pragma unroll
    for(int kk=0;kk<2;kk++){
      int tc = kk*4+ks;
      bf16x8 a[4], b[4];
      #pragma unroll
      for(int fm=0;fm<4;fm++)
        a[fm] = *(const bf16x8*)(wpk + ((size_t)((s*8+tc)*64 + fm*16+l15))*8);
      #pragma unroll
      for(int fm=0;fm<4;fm++) asm volatile("" : "+v"(a[fm]));
      #pragma unroll
      for(int fn=0;fn<4;fn++) b[fn] = *(const bf16x8*)(&sB[(size_t)(tc*256 + w_*64+fn*16+l15)*8]);
      #pragma unroll
      for(int fm=0;fm<4;fm++)
        #pragma unroll
        for(int fn=0;fn<4;fn++)
          acc[fm][fn] = __builtin_amdgcn_mfma_f32_16x16x32_bf16(a[fm], b[fn], acc[fm][fn], 0,0,0);
    }
  }
  #pragma unroll
  for(int fm=0;fm<4;fm++){
    int oc0 = fm*16 + ks*4;
    #pragma unroll
    for(int fn=0;fn<4;fn++){
      int pxt = px0 + w_*64 + fn*16 + l15;
      union{ uint2 u; bf16 h[4]; } pk;
      #pragma unroll
      for(int j=0;j<4;j++) pk.h[j]=__float2bfloat16(fmaxf(acc[fm][fn][j]+bias[oc0+j],0.f));
      *(uint2*)(outN + (size_t)pxt*64 + oc0) = pk.u;
    }
  }
}

// ---------------- routing select -> featN (96ch) + fused timep tail blocks ----------------
__global__ void k_routeT(const bf16* __restrict__ xs, const bf16* __restrict__ xm,
                         const bf16* __restrict__ xh, const float* __restrict__ xseg,
                         const float* __restrict__ scalp, const float* __restrict__ tl,
                         const float* __restrict__ tr, bf16* __restrict__ featN,
                         int nroute, float* __restrict__ dtp){
  __shared__ float sh[256];
  int bidx = blockIdx.x;
  float tl0 = tl[0], tr0 = tr[0], thr = tl0+tr0;
  if(bidx >= nroute){
    int b = bidx - nroute, t = threadIdx.x;
    float v=0.f;
    if(t<25){
      float sz=scalp[b*25+t];
      v = (sz>thr) ? 1e-4f*(sz-thr) : ((sz>=tl0 && sz<=thr) ? 2e-4f*tr0 : 3e-4f*(tl0-sz));
    }
    sh[t]=v; __syncthreads();
    for(int o=128;o>0;o>>=1){ if(t<o) sh[t]+=sh[t+o]; __syncthreads(); }
    if(t==0) dtp[b]=sh[0]*(1.f/25.f);
    return;
  }
  int idx = bidx*256+threadIdx.x;
  int c = idx%12; int px = idx/12;
  int b = px/25600; int rem = px - b*25600;
  int y = rem/160, xx = rem - y*160;
  int n = b*25 + (y>>5)*5 + (xx>>5);
  float sz = scalp[n];
  const bf16* src = (sz>thr) ? xs : ((sz>=tl0 && sz<=thr) ? xm : xh);
  uint4 v = make_uint4(0,0,0,0);
  if(c < 8){
    v = *(const uint4*)(src + ((size_t)n*1024 + ((y&31)<<5) + (xx&31))*64 + c*8);
  } else if(c == 8){
    union{ uint4 q; bf16 h[8]; } pk;
    pk.q = make_uint4(0,0,0,0);
    pk.h[0]=__float2bfloat16(xseg[(b*3+0)*25600 + rem]-MEAN0);
    pk.h[1]=__float2bfloat16(xseg[(b*3+1)*25600 + rem]-MEAN1);
    pk.h[2]=__float2bfloat16(xseg[(b*3+2)*25600 + rem]-MEAN2);
    v = pk.q;
  }
  *(uint4*)(featN + (size_t)px*96 + c*8) = v;
}

// ---------------- MARM MFMA: 96ch NHWC bf16 conv3x3 -> 64ch NHWC bf16, relu ----------------
__global__ __launch_bounds__(256,2) void k_marmM(const bf16* __restrict__ featN,
                        const bf16* __restrict__ wpm, const float* __restrict__ bias,
                        bf16* __restrict__ outN){
  __shared__ __align__(16) __bf16 sB[12*340*8];  // 65280 B
  __shared__ __align__(16) __bf16 sA[12*64*8];   // 12288 B
  int bid = blockIdx.x;
  int img = bid/100; int t_ = bid - img*100;
  int y0 = (t_/5)*8, x0 = (t_%5)*32;
  int tid = threadIdx.x;
  const bf16* ib = featN + (size_t)img*25600*96;
  for(int cid=tid; cid<4080; cid+=256){
    int icg = cid/340, p = cid - icg*340;
    int r = p/34, cc = p - r*34;
    int gy = y0-1+r, gx = x0-1+cc;
    float4 v = {0.f,0.f,0.f,0.f};
    if((unsigned)gy<160u && (unsigned)gx<160u)
      v = *(const float4*)(ib + (size_t)(gy*160+gx)*96 + icg*8);
    *(float4*)(&sB[(size_t)(icg*340+p)*8]) = v;
  }
  for(int cid=tid; cid<768; cid+=256)
    *(float4*)(&sA[(size_t)cid*8]) = ((const float4*)wpm)[cid];
  __syncthreads();
  int w_ = tid>>6, l = tid&63;
  int ks = l>>4, l15 = l&15;
  f32x4 acc[4][4];
  #pragma unroll
  for(int i=0;i<4;i++)
    #pragma unroll
    for(int j=0;j<4;j++) acc[i][j]=(f32x4){0.f,0.f,0.f,0.f};
  int pr[4], pc[4];
  #pragma unroll
  for(int fn=0;fn<4;fn++){ int npx = w_*64+fn*16+l15; pr[fn]=npx>>5; pc[fn]=npx&31; }
  float4 pre[3];
  for(int tap=0;tap<9;tap++){
    if(tap<8){
      #pragma unroll
      for(int k=0;k<3;k++) pre[k] = ((const float4*)wpm)[(tap+1)*768 + k*256 + tid];
    }
    int ty=tap/3, tx=tap-ty*3;
    #pragma unroll
    for(int kk=0;kk<3;kk++){
      int tc = kk*4+ks;
      bf16x8 a[4], b[4];
      #pragma unroll
      for(int fm=0;fm<4;fm++) a[fm] = *(const bf16x8*)(&sA[(size_t)(tc*64 + fm*16+l15)*8]);
      #pragma unroll
      for(int fn=0;fn<4;fn++)
        b[fn] = *(const bf16x8*)(&sB[(size_t)(tc*340 + (pr[fn]+ty)*34 + pc[fn]+tx)*8]);
      #pragma unroll
      for(int fm=0;fm<4;fm++)
        #pragma unroll
        for(int fn=0;fn<4;fn++)
          acc[fm][fn] = __builtin_amdgcn_mfma_f32_16x16x32_bf16(a[fm], b[fn], acc[fm][fn], 0,0,0);
    }
    if(tap<8){
      __syncthreads();
      #pragma unroll
      for(int k=0;k<3;k++) ((float4*)sA)[k*256+tid] = pre[k];
      __syncthreads();
    }
  }
  bf16* ob = outN + (size_t)img*25600*64;
  #pragma unroll
  for(int fm=0;fm<4;fm++){
    int oc0 = fm*16 + ks*4;
    #pragma unroll
    for(int fn=0;fn<4;fn++){
      int px = (y0+pr[fn])*160 + x0+pc[fn];
      union{ uint2 u; bf16 h[4]; } pk;
      #pragma unroll
      for(int j=0;j<4;j++) pk.h[j]=__float2bfloat16(fmaxf(acc[fm][fn][j]+bias[oc0+j],0.f));
      *(uint2*)(ob + (size_t)px*64 + oc0) = pk.u;
    }
  }
}

// ---------------- MFMA up-conv v5 (round-11 config, occupancy 3): 64->256 conv3x3 + ps(2) + relu ----------------
template<int H, int W>
__global__ __launch_bounds__(256,3) void k_convup(const bf16* __restrict__ in,
                        bf16* __restrict__ o0, bf16* __restrict__ o1,
                        const bf16* __restrict__ wp, const float* __restrict__ bias){
  constexpr int TXC = W/16, TPB = (H/4)*TXC;
  __shared__ __align__(16) char smem[16384];
  __bf16* sB = (__bf16*)smem;
  int bid = blockIdx.x;
  int img = bid/TPB; int t_ = bid - img*TPB;
  int y0 = (t_/TXC)*4, x0 = (t_%TXC)*16;
  int tid = threadIdx.x;
  const bf16* ib = in + (size_t)img*H*W*64;
  for(int cid=tid; cid<864; cid+=256){
    int p = cid>>3, tt = cid&7;
    int r = p/18, cc = p - r*18;
    int gy = y0-1+r, gx = x0-1+cc;
    float4 v = {0.f,0.f,0.f,0.f};
    if((unsigned)gy<(unsigned)H && (unsigned)gx<(unsigned)W)
      v = *(const float4*)(ib + ((size_t)(gy*W+gx)*64 + tt*8));
    *(float4*)(&sB[(size_t)(p*8 + (tt^(p&7)))*8]) = v;
  }
  __syncthreads();
  int w_ = tid>>6, l = tid&63;
  int ks = l>>4, l15 = l&15;
  f32x4 acc[4][4];
  #pragma unroll
  for(int i=0;i<4;i++)
    #pragma unroll
    for(int j=0;j<4;j++) acc[i][j]=(f32x4){0.f,0.f,0.f,0.f};
  const bf16* wpb = wp + ((size_t)w_*64 + l15)*8;
  #pragma unroll
  for(int kk=0;kk<2;kk++){
    int tc = kk*4+ks;
    #pragma unroll
    for(int tr=0;tr<3;tr++){
      bf16x8 afr[3][4];
      #pragma unroll
      for(int tx=0;tx<3;tx++)
        #pragma unroll
        for(int fm=0;fm<4;fm++)
          afr[tx][fm] = *(const bf16x8*)(wpb + ((size_t)(((tr*3+tx)*8+tc)*256) + fm*16)*8);
      #pragma unroll
      for(int tx=0;tx<3;tx++)
        #pragma unroll
        for(int fm=0;fm<4;fm++)
          asm volatile("" : "+v"(afr[tx][fm]));
      #pragma unroll
      for(int tx=0;tx<3;tx++){
        bf16x8 b[4];
        #pragma unroll
        for(int fn=0;fn<4;fn++){
          int p = (fn+tr)*18 + l15+tx;
          b[fn] = *(const bf16x8*)(&sB[(size_t)(p*8 + (tc^(p&7)))*8]);
        }
        #pragma unroll
        for(int fm=0;fm<4;fm++)
          #pragma unroll
          for(int fn=0;fn<4;fn++)
            acc[fm][fn] = __builtin_amdgcn_mfma_f32_16x16x32_bf16(afr[tx][fm], b[fn], acc[fm][fn], 0,0,0);
      }
    }
  }
  bf16* ob = ((img&1) ? o1 : o0) + (size_t)(img>>1)*((size_t)8*H*W*64);
  const int W2 = 2*W;
  char* oT = smem;
  #pragma unroll
  for(int h=0;h<2;h++){
    __syncthreads();
    #pragma unroll
    for(int fm=0;fm<4;fm++){
      int co = w_*16 + fm*4 + ks;
      #pragma unroll
      for(int j=0;j<4;j++){
        float bsv = bias[w_*64 + fm*16 + ks*4 + j];
        int r1=(j>>1)&1, r2=j&1;
        #pragma unroll
        for(int ff=0;ff<2;ff++){
          int fn = 2*h+ff;
          int opx = (2*ff+r1)*32 + 2*l15+r2;
          float v = fmaxf(acc[fm][fn][j]+bsv, 0.f);
          int sl = (co>>3) ^ ((opx>>1)&7);
          *(bf16*)(oT + opx*128 + sl*16 + (co&7)*2) = __float2bfloat16(v);
        }
      }
    }
    __syncthreads();
    #pragma unroll
    for(int k=0;k<4;k++){
      int cid = k*256 + tid;
      int p = cid>>3, lq = cid&7;
      int sl = lq ^ ((p>>1)&7);
      uint4 v = *(const uint4*)(oT + p*128 + sl*16);
      int Y = 2*y0 + 4*h + (p>>5), X = 2*x0 + (p&31);
      *(uint4*)(ob + ((size_t)Y*W2 + X)*64 + lq*8) = v;
    }
  }
}

// ---------------- final conv MFMA (2 images per dispatch): writes y, xcropia, xoutputa ----------------
__global__ __launch_bounds__(256,3) void k_upcM(const bf16* __restrict__ i0,
                        const bf16* __restrict__ i1, const bf16* __restrict__ wpu,
                        const float* __restrict__ bias, const float* __restrict__ scal,
                        float* __restrict__ dout, int b0){
  __shared__ __align__(16) __bf16 sB[396*64];   // 50688 B
  int tid = threadIdx.x;
  int img = blockIdx.x/1600; int t_ = blockIdx.x - img*1600;
  const bf16* in = img ? i1 : i0;
  int b = b0 + img;
  int by0 = (t_/10)*4, bx0 = (t_%10)*64;
  for(int cid=tid; cid<3168; cid+=256){
    int px = cid>>3, c = cid&7;
    int hr = px/66, hc = px - hr*66;
    int gy = by0-1+hr, gx = bx0-1+hc;
    float4 v = {0.f,0.f,0.f,0.f};
    if((unsigned)gy<640u && (unsigned)gx<640u)
      v = *(const float4*)(in + ((size_t)(gy*640+gx))*64 + c*8);
    int slot = c ^ (px&7);
    *(float4*)(&sB[(size_t)px*64 + slot*8]) = v;
  }
  int w_ = tid>>6, l = tid&63;
  int ks = l>>4, l15 = l&15;
  bf16x8 afr[9][2];
  #pragma unroll
  for(int tap=0;tap<9;tap++)
    #pragma unroll
    for(int kk=0;kk<2;kk++)
      afr[tap][kk] = *(const bf16x8*)(wpu + (size_t)((tap*8 + kk*4+ks)*16 + l15)*8);
  __syncthreads();
  f32x4 acc[4];
  #pragma unroll
  for(int fn=0;fn<4;fn++) acc[fn]=(f32x4){0.f,0.f,0.f,0.f};
  int r = w_;
  int cxc[4];
  #pragma unroll
  for(int fn=0;fn<4;fn++) cxc[fn]=fn*16+l15;
  for(int tap=0;tap<9;tap++){
    int ty=tap/3, tx=tap-ty*3;
    #pragma unroll
    for(int kk=0;kk<2;kk++){
      int tc = kk*4+ks;
      #pragma unroll
      for(int fn=0;fn<4;fn++){
        int ph = (r+ty)*66 + cxc[fn]+tx;
        int slot = tc ^ (ph&7);
        bf16x8 bb = *(const bf16x8*)(&sB[(size_t)ph*64 + slot*8]);
        acc[fn] = __builtin_amdgcn_mfma_f32_16x16x32_bf16(afr[tap][kk], bb, acc[fn], 0,0,0);
      }
    }
  }
  if(ks==0){
    float c0=bias[0]+MEAN0, c1=bias[1]+MEAN1, c2=bias[2]+MEAN2;
    int gy = by0 + r;
    size_t yb=(size_t)b*3*409600;
    #pragma unroll
    for(int fn=0;fn<4;fn++){
      int gx = bx0 + cxc[fn];
      float a0=acc[fn][0]+c0, a1=acc[fn][1]+c1, a2=acc[fn][2]+c2;
      int n=b*25+(gy>>7)*5+(gx>>7);
      float sv=scal[128+n];
      size_t pidx=(size_t)gy*640+gx;
      dout[yb+pidx]=a0; dout[yb+409600+pidx]=a1; dout[yb+819200+pidx]=a2;
      dout[4915204 + (size_t)b*409600 + pidx]=sv;
      size_t xa=6553604+yb;
      dout[xa+pidx]=a0*sv; dout[xa+409600+pidx]=a1*sv; dout[xa+819200+pidx]=a2*sv;
    }
  }
}

extern "C" void kernel_launch(void* const* d_in, const int* in_sizes, int n_in,
                              void* d_out, int out_size, void* d_ws, size_t ws_size,
                              hipStream_t stream){
  const float* x     =(const float*)d_in[0];
  const float* tl    =(const float*)d_in[1];
  const float* tr    =(const float*)d_in[2];
  const float* iicm_w=(const float*)d_in[3];
  const float* iicm_b=(const float*)d_in[4];
  const float* conv4_w=(const float*)d_in[5];
  const float* conv4_b=(const float*)d_in[6];
  const float* b1_w1 =(const float*)d_in[7];  const float* b1_b1=(const float*)d_in[8];
  const float* b1_w2 =(const float*)d_in[9];  const float* b1_b2=(const float*)d_in[10];
  const float* c1_w  =(const float*)d_in[11]; const float* c1_b =(const float*)d_in[12];
  const float* b2_w1 =(const float*)d_in[13]; const float* b2_b1=(const float*)d_in[14];
  const float* b2_w2 =(const float*)d_in[15]; const float* b2_b2=(const float*)d_in[16];
  const float* c2_w  =(const float*)d_in[17]; const float* c2_b =(const float*)d_in[18];
  const float* b3_w1 =(const float*)d_in[19]; const float* b3_b1=(const float*)d_in[20];
  const float* b3_w2 =(const float*)d_in[21]; const float* b3_b2=(const float*)d_in[22];
  const float* c3_w  =(const float*)d_in[23]; const float* c3_b =(const float*)d_in[24];
  const float* marm_w=(const float*)d_in[25]; const float* marm_b=(const float*)d_in[26];
  const float* up1_w =(const float*)d_in[27]; const float* up1_b=(const float*)d_in[28];
  const float* up2_w =(const float*)d_in[29]; const float* up2_b=(const float*)d_in[30];
  const float* upc_w =(const float*)d_in[31]; const float* upc_b=(const float*)d_in[32];

  char* base = (char*)d_ws;
  float* out =(float*)d_out;
  float* scal=(float*)base;
  float* partial=(float*)(base+1024);

  const int SEG = (ws_size >= 188417024ull) ? 4 : 1;
  const int NP  = SEG*25;
  const int NPix= NP*1024;

  const size_t SZB = (size_t)NP*131072;
  char* bufs = base + 8192;
  bf16* fN   = (bf16*)(bufs + 0*SZB);
  bf16* tmpN = (bf16*)(bufs + 1*SZB);
  bf16* xsN  = (bf16*)(bufs + 2*SZB);
  bf16* b1oN = (bf16*)(bufs + 3*SZB);
  bf16* b2oN = (bf16*)(bufs + 4*SZB);
  bf16* xmN  = (bf16*)(bufs + 5*SZB);
  bf16* b3oN = (bf16*)(bufs + 6*SZB);
  bf16* xhN  = (bf16*)(bufs + 7*SZB);
  bf16* featN= (bf16*)(bufs + 0*SZB);
  bf16* marmN= (bf16*)(bufs + 2*SZB);
  bf16* ps1  = (bf16*)(bufs + 4*SZB);
  bf16* ps2a = (bf16*)(bufs + 8*SZB);
  bf16* ps2b = (bf16*)(bufs + 0*SZB);
  char* packsp = bufs + 8*SZB + 52428800;
  bf16* wpc  = (bf16*)packsp;                       // 36864
  bf16* wp1  = wpc + 36864;                         // 147456
  bf16* wp2  = wp1 + 147456;                        // 147456
  bf16* wpm  = wp2 + 147456;                        // 55296
  bf16* wpu  = wpm + 55296;                         // 9216
  bf16* wpg2 = wpu + 9216;                          // 61440
  bf16* wp4  = wpg2 + 61440;                        // 10240
  bf16* f16N = wp4 + 10240;                         // NP*16384 bf16

  k_wpack<<<1829,256,0,stream>>>(c1_w,c2_w,c3_w, up1_w,up2_w, marm_w, upc_w,
                                 b1_w1,b1_w2,b2_w1,b2_w2,b3_w1,b3_w2, conv4_w, wpc);

  for(int b0=0;b0<4;b0+=SEG){
    int p0 = b0*25;
    const float* xseg = x + (size_t)b0*3*25600;
    float* scalp = scal + p0;

    k_iicm <<<NP*4,  256,0,stream>>>(xseg, iicm_w, iicm_b, f16N, partial);
    k_conv4M<<<NP*8+NP, 128,0,stream>>>(f16N, wp4, conv4_b, fN, partial, scalp, NP*8);
    // block 1
    k_gconvM<<<NP*8, 128,0,stream>>>(fN,   wpg2,         b1_b1, (const bf16*)0, tmpN, 1);
    k_gconvM<<<NP*8, 128,0,stream>>>(tmpN, wpg2+10240,   b1_b2, fN,             b1oN, 0);
    k_1x1M <<<NP*4,  256,0,stream>>>(fN, b1oN, (const bf16*)0, (const bf16*)0, 2, wpc, c1_b, xsN);
    // block 2
    k_gconvM<<<NP*8, 128,0,stream>>>(xsN,  wpg2+2*10240, b2_b1, (const bf16*)0, tmpN, 1);
    k_gconvM<<<NP*8, 128,0,stream>>>(tmpN, wpg2+3*10240, b2_b2, xsN,            b2oN, 0);
    k_1x1M <<<NP*4,  256,0,stream>>>(fN, b1oN, b2oN, (const bf16*)0, 3, wpc+8192, c2_b, xmN);
    // block 3
    k_gconvM<<<NP*8, 128,0,stream>>>(xmN,  wpg2+4*10240, b3_b1, (const bf16*)0, tmpN, 1);
    k_gconvM<<<NP*8, 128,0,stream>>>(tmpN, wpg2+5*10240, b3_b2, xmN,            b3oN, 0);
    k_1x1M <<<NP*4,  256,0,stream>>>(fN, b1oN, b2oN, b3oN, 4, wpc+20480, c3_b, xhN);
    // routing -> featN (96ch NHWC) + fused timep
    k_routeT<<<NP*48+SEG,256,0,stream>>>(xsN, xmN, xhN, xseg, scalp, tl, tr, featN,
                                         NP*48, out + 4915200 + b0);
    // MARM + upsample chain
    k_marmM<<<SEG*100, 256,0,stream>>>(featN, wpm, marm_b, marmN);
    k_convup<160,160><<<SEG*400, 256,0,stream>>>(marmN, ps1, ps1 + 6553600, wp1, up1_b);
    for(int i=0;i<SEG;i+=2){
      int ni = (SEG-i>=2)?2:1;
      k_convup<320,320><<<ni*1600, 256,0,stream>>>(ps1 + (size_t)i*6553600, ps2a, ps2b, wp2, up2_b);
      k_upcM<<<ni*1600,256,0,stream>>>(ps2a, ps2b, wpu, upc_b, scal, out, b0+i);
    }
  }
}